// Round 5
// baseline (68.744 us; speedup 1.0000x reference)
//
#include <hip/hip_runtime.h>

// CRF forward partition via ergodic chunked scan.
// B=256, T=1024, K=50. Chunks of S=32 steps with H=6 halo steps; the
// transition operator's contraction makes chunk states exact up to an
// additive scalar, recovered by chaining reference-lane values.
//
// R5 change: NO per-lane arrays anywhere in crf_chunk. R1-R4 all compiled to
// VGPR_Count=32 because hipcc kept the E array in scratch (private mem);
// scratch reloads (L1/L2, invisible in FETCH/WRITE) added ~25 loads/step.
// E pairs now live in 25 NAMED scalar registers (et0..et24, macro-expanded),
// feats prefetch ring in named f0..f3/n0..n3. Inner product stays
// v_dot2_f32_f16 on packed-f16 pairs, e-vector packed via DPP swap + pkrtz.

#define KTAGS 50
#define TLEN 1024
#define NBATCH 256
#define SCHUNK 32
#define HALO 6
#define NCH (TLEN / SCHUNK)   // 32
#define START_TAG 48
#define STOP_TAG 49

typedef _Float16 half2_t __attribute__((ext_vector_type(2)));

__device__ __forceinline__ float lane_bcast_f(float v, int l) {
  return __uint_as_float((unsigned)__builtin_amdgcn_readlane((int)__float_as_uint(v), l));
}

__device__ __forceinline__ float swap1(float x) {
  // quad_perm(1,0,3,2) = lane ^ 1
  return __uint_as_float((unsigned)__builtin_amdgcn_mov_dpp(
      (int)__float_as_uint(x), 0xB1, 0xF, 0xF, true));
}

__device__ __forceinline__ float fdot2(unsigned a2, unsigned b2, float c) {
  return __builtin_amdgcn_fdot2(__builtin_bit_cast(half2_t, a2),
                                __builtin_bit_cast(half2_t, b2), c, false);
}

__device__ __forceinline__ unsigned pk16(float lo, float hi) {
  return __builtin_bit_cast(unsigned, __builtin_amdgcn_cvt_pkrtz(lo, hi));
}

// ---- setup: detect mask layout (uint8 bool vs 4-byte) + lengths under uint8.
// Reads only the first B*T bytes (safe for either layout). viol goes in the
// sign bit of len8[b]; a 4-byte layout always trips viol on some row.
__global__ __launch_bounds__(64) void crf_setup(const unsigned char* __restrict__ mask,
                                                int* __restrict__ len8) {
  const int b = blockIdx.x;
  const int lane = threadIdx.x;
  const uint4* row = reinterpret_cast<const uint4*>(mask + (size_t)b * TLEN);
  uint4 q = row[lane];
  unsigned w[4] = {q.x, q.y, q.z, q.w};
  int viol = 0;
  int cnt = 0;
  unsigned prev_last = 1u;
  #pragma unroll
  for (int k = 0; k < 4; ++k) {
    unsigned x = w[k];
    viol |= !(x == 0x01010101u || x == 0x00010101u || x == 0x00000101u ||
              x == 0x00000001u || x == 0u);
    unsigned first = x & 0xffu;
    if (k > 0) viol |= (prev_last == 0u && first != 0u);
    prev_last = (x >> 24) & 0xffu;
    cnt += __popc(x);  // bytes are 0/1 when valid
  }
  unsigned firstbyte = w[0] & 0xffu;
  unsigned pl = (unsigned)__shfl_up((int)prev_last, 1);
  if (lane == 0) viol |= (firstbyte == 0u);        // row must start with 1
  else           viol |= (pl == 0u && firstbyte != 0u);
  for (int off = 32; off > 0; off >>= 1) {
    cnt  += __shfl_xor(cnt, off);
    viol |= __shfl_xor(viol, off);
  }
  if (lane == 0) len8[b] = cnt | (viol ? (int)0x80000000 : 0);
}

__global__ __launch_bounds__(64) void crf_lenfix(const unsigned char* __restrict__ mask,
                                                 const int* __restrict__ len8,
                                                 int* __restrict__ lengths) {
  const int b = blockIdx.x;
  const int lane = threadIdx.x;
  int acc = 0;
  #pragma unroll
  for (int k = 0; k < 4; ++k) acc |= len8[lane + 64 * k];
  for (int off = 32; off > 0; off >>= 1) acc |= __shfl_xor(acc, off);
  if (acc >= 0) {   // no violation anywhere: uint8 layout confirmed
    if (lane == 0) lengths[b] = len8[b] & 0x7fffffff;
    return;
  }
  // 4-byte layout: count nonzero 32-bit words (works for int32 and float masks)
  const int4* row = reinterpret_cast<const int4*>((const int*)mask + (size_t)b * TLEN);
  int cnt = 0;
  #pragma unroll
  for (int k = 0; k < 4; ++k) {
    int4 v = row[lane + 64 * k];
    cnt += (v.x != 0) + (v.y != 0) + (v.z != 0) + (v.w != 0);
  }
  for (int off = 32; off > 0; off >>= 1) cnt += __shfl_xor(cnt, off);
  if (lane == 0) lengths[b] = cnt;
}

// X-macro list over the 25 E pairs: (index, lane = 2*index)
#define ET_LIST(X) \
  X(0) X(1) X(2) X(3) X(4) X(5) X(6) X(7) X(8) X(9) X(10) X(11) X(12) \
  X(13) X(14) X(15) X(16) X(17) X(18) X(19) X(20) X(21) X(22) X(23) X(24)

// ---- main: one wave per (batch, chunk). Lane j owns alpha[j] and column j
// of E = exp(trans) as 25 packed-f16 pairs in NAMED registers. Per step:
//   m = alpha[lane 1] (always finite, within ~8 of max)
//   e = min(exp(alpha - m), 6e4); epk = (e_L, e_{L^1}) via DPP+pkrtz
//   s_j = sum_g dot2(readlane(epk, 2g), et_g)      [f32 accumulate]
//   alpha = log(s) + m + feat[t]
// Rows 0 and 49 of E are identically 0 (NEG mask), so dead tags contribute 0.
__global__ __launch_bounds__(64, 4) void crf_chunk(const float* __restrict__ feats,
                                                   const float* __restrict__ trans,
                                                   const int* __restrict__ lengths,
                                                   float* __restrict__ rho,
                                                   float* __restrict__ sigma,
                                                   float* __restrict__ rfin) {
  const int c = blockIdx.x;   // chunk
  const int b = blockIdx.y;   // batch
  const int len = lengths[b];
  if (c != 0 && c * SCHUNK >= len) return;   // c==0 always active (len>=1)
  const int lane = threadIdx.x;
  const int jj = lane < KTAGS ? lane : KTAGS - 1;   // clamp for in-bounds
  const bool valid = lane < KTAGS;

  // 25 named registers holding column j of E, packed f16 pairs along i.
  // exp(-10000)=0 kills NEG edges; pkrtz(0)=0 preserves them exactly.
#define ET_DECL(g) unsigned et##g;
  ET_LIST(ET_DECL)
#undef ET_DECL
#define ET_INIT(g) et##g = pk16(__expf(trans[(2*(g)) * KTAGS + jj]), \
                                __expf(trans[(2*(g)+1) * KTAGS + jj]));
  ET_LIST(ET_INIT)
#undef ET_INIT

  const float* fb = feats + (size_t)b * TLEN * KTAGS;
  const int t_end = min((c + 1) * SCHUNK, len) - 1;   // inclusive
  const int t_rho = (c != 0) ? c * SCHUNK - 1 : -99;

  float alpha;
  int t_begin;
  if (c == 0) {
    alpha = valid ? (fb[jj] + trans[START_TAG * KTAGS + jj]) : -1e30f;  // exact init
    t_begin = 1;
  } else {
    const int t0 = c * SCHUNK - 1 - HALO;   // >= 25
    alpha = fb[t0 * KTAGS + jj];            // arbitrary init; halo mixes it out
    t_begin = t0 + 1;
  }

#define RL(L) ((unsigned)__builtin_amdgcn_readlane((int)epk, (L)))
  auto step = [&](float f_cur) {
    float m_ = lane_bcast_f(alpha, 1);
    float e_ = __expf(alpha - m_);
    e_ = fminf(e_, 60000.f);                 // f16-safe (never triggers in practice)
    unsigned epk = pk16(e_, swap1(e_));      // even lane L holds (e_L, e_{L+1})
    float s0 = 0.f, s1 = 0.f, s2 = 0.f, s3 = 0.f;
    s0 = fdot2(RL(0),  et0,  s0);  s1 = fdot2(RL(2),  et1,  s1);
    s2 = fdot2(RL(4),  et2,  s2);  s3 = fdot2(RL(6),  et3,  s3);
    s0 = fdot2(RL(8),  et4,  s0);  s1 = fdot2(RL(10), et5,  s1);
    s2 = fdot2(RL(12), et6,  s2);  s3 = fdot2(RL(14), et7,  s3);
    s0 = fdot2(RL(16), et8,  s0);  s1 = fdot2(RL(18), et9,  s1);
    s2 = fdot2(RL(20), et10, s2);  s3 = fdot2(RL(22), et11, s3);
    s0 = fdot2(RL(24), et12, s0);  s1 = fdot2(RL(26), et13, s1);
    s2 = fdot2(RL(28), et14, s2);  s3 = fdot2(RL(30), et15, s3);
    s0 = fdot2(RL(32), et16, s0);  s1 = fdot2(RL(34), et17, s1);
    s2 = fdot2(RL(36), et18, s2);  s3 = fdot2(RL(38), et19, s3);
    s0 = fdot2(RL(40), et20, s0);  s1 = fdot2(RL(42), et21, s1);
    s2 = fdot2(RL(44), et22, s2);  s3 = fdot2(RL(46), et23, s3);
    s0 = fdot2(RL(48), et24, s0);
    float s_ = (s0 + s1) + (s2 + s3);
    alpha = __logf(s_) + m_ + f_cur;   // log(0) = -inf: dead tags stay dead
  };
#undef RL

  // 4-deep feats prefetch ring, all named scalars (no arrays -> no scratch).
  float f0, f1, f2, f3;
  {
    int a0 = t_begin + 0 > t_end ? t_end : t_begin + 0;
    int a1 = t_begin + 1 > t_end ? t_end : t_begin + 1;
    int a2 = t_begin + 2 > t_end ? t_end : t_begin + 2;
    int a3 = t_begin + 3 > t_end ? t_end : t_begin + 3;
    f0 = fb[a0 * KTAGS + jj]; f1 = fb[a1 * KTAGS + jj];
    f2 = fb[a2 * KTAGS + jj]; f3 = fb[a3 * KTAGS + jj];
  }
  for (int tb = t_begin; tb <= t_end; tb += 4) {
    int a0 = tb + 4 > t_end ? t_end : tb + 4;
    int a1 = tb + 5 > t_end ? t_end : tb + 5;
    int a2 = tb + 6 > t_end ? t_end : tb + 6;
    int a3 = tb + 7 > t_end ? t_end : tb + 7;
    float n0 = fb[a0 * KTAGS + jj];
    float n1 = fb[a1 * KTAGS + jj];
    float n2 = fb[a2 * KTAGS + jj];
    float n3 = fb[a3 * KTAGS + jj];
    {
      step(f0);
      if (tb + 0 == t_rho && lane == 1) rho[b * NCH + c] = alpha;
    }
    if (tb + 1 <= t_end) {
      step(f1);
      if (tb + 1 == t_rho && lane == 1) rho[b * NCH + c] = alpha;
    }
    if (tb + 2 <= t_end) {
      step(f2);
      if (tb + 2 == t_rho && lane == 1) rho[b * NCH + c] = alpha;
    }
    if (tb + 3 <= t_end) {
      step(f3);
      if (tb + 3 == t_rho && lane == 1) rho[b * NCH + c] = alpha;
    }
    f0 = n0; f1 = n1; f2 = n2; f3 = n3;
  }
  if (lane == 1) sigma[b * NCH + c] = alpha;   // frame ref at chunk end

  if (len <= (c + 1) * SCHUNK) {
    // final chunk for this batch: r = LSE_i(alpha_i + trans[i, STOP])
    float x = valid ? (alpha + trans[jj * KTAGS + STOP_TAG]) : -1e30f;
    float m2 = x;
    for (int off = 32; off > 0; off >>= 1) m2 = fmaxf(m2, __shfl_xor(m2, off));
    float es = __expf(x - m2);
    for (int off = 32; off > 0; off >>= 1) es += __shfl_xor(es, off);
    float r = __logf(es) + m2;
    if (lane == 0) rfin[b * NCH + c] = r;
  }
}

// ---- combine: chain scalar offsets, pick final chunk's LSE, reduce over b.
__global__ __launch_bounds__(256) void crf_combine(const int* __restrict__ lengths,
                                                   const float* __restrict__ rho,
                                                   const float* __restrict__ sigma,
                                                   const float* __restrict__ rfin,
                                                   float* __restrict__ out) {
  const int b = threadIdx.x;
  const int len = lengths[b];
  const int nch = (len + SCHUNK - 1) / SCHUNK;
  float delta = 0.f;
  for (int c = 1; c < nch; ++c)
    delta += sigma[b * NCH + c - 1] - rho[b * NCH + c];
  float res = rfin[b * NCH + nch - 1] + delta;
  __shared__ float red[256];
  red[b] = res;
  __syncthreads();
  for (int s = 128; s > 0; s >>= 1) {
    if (b < s) red[b] += red[b + s];
    __syncthreads();
  }
  if (b == 0) out[0] = red[0];
}

extern "C" void kernel_launch(void* const* d_in, const int* in_sizes, int n_in,
                              void* d_out, int out_size, void* d_ws, size_t ws_size,
                              hipStream_t stream) {
  const float* feats = (const float*)d_in[0];
  const float* trans = (const float*)d_in[1];
  const unsigned char* mask = (const unsigned char*)d_in[2];
  float* out = (float*)d_out;

  // workspace layout (~100 KB)
  int* len8 = (int*)d_ws;                    // 256 ints
  int* lengths = len8 + 256;                 // 256 ints
  float* rho = (float*)(lengths + 256);      // B*NCH
  float* sigma = rho + NBATCH * NCH;         // B*NCH
  float* rfin = sigma + NBATCH * NCH;        // B*NCH

  crf_setup<<<NBATCH, 64, 0, stream>>>(mask, len8);
  crf_lenfix<<<NBATCH, 64, 0, stream>>>(mask, len8, lengths);
  dim3 grid(NCH, NBATCH);
  crf_chunk<<<grid, 64, 0, stream>>>(feats, trans, lengths, rho, sigma, rfin);
  crf_combine<<<1, 256, 0, stream>>>(lengths, rho, sigma, rfin, out);
}